// Round 12
// baseline (97.160 us; speedup 1.0000x reference)
//
#include <hip/hip_runtime.h>
#include <hip/hip_bf16.h>

typedef float f32x4 __attribute__((ext_vector_type(4)));
typedef __bf16 bf16x8 __attribute__((ext_vector_type(8)));

#define INF   8192             // in_features
#define FOLDS 127
#define LOCAL 128
#define OUTF  (FOLDS * LOCAL)  // 16256
#define BM    64               // batch rows per block
#define BN    64               // output features per block (half a fold)

// As/Bs: 64 rows x 128 cols bf16 (row stride 256B), XOR swizzle byte ^= (row&7)<<4
__device__ __forceinline__ void cvt_store8(char* lds, int byte, f32x4 v0, f32x4 v1) {
    bf16x8 w;
    w[0] = (__bf16)v0[0]; w[1] = (__bf16)v0[1]; w[2] = (__bf16)v0[2]; w[3] = (__bf16)v0[3];
    w[4] = (__bf16)v1[0]; w[5] = (__bf16)v1[1]; w[6] = (__bf16)v1[2]; w[7] = (__bf16)v1[3];
    *(bf16x8*)(lds + byte) = w;
}

__global__ __launch_bounds__(256, 5)   // 32 KB LDS -> 5 blocks/CU, 20 waves/CU
void local_linear_kernel(const float* __restrict__ x,
                         const float* __restrict__ W,
                         const float* __restrict__ bias,
                         float* __restrict__ out)
{
    __shared__ __align__(16) __bf16 As[BM * 128];   // x tile, 16 KiB
    __shared__ __align__(16) __bf16 Bs[BN * 128];   // W half-fold, 16 KiB

    // Grid order: fn FAST (blockIdx.x), mt SLOW (blockIdx.y). Concurrently
    // resident blocks then share one batch tile and together write 64
    // COMPLETE output rows (contiguous 4.2 MB) instead of thin column
    // strips scattered over the whole 133 MB output -> HBM write locality.
    const int fn = blockIdx.x;          // fold-half 0..253
    const int mt = blockIdx.y;          // batch tile 0..31
    const int f  = fn >> 1;             // fold 0..126
    const int bn0 = (fn & 1) * BN;      // 0 or 64 within the fold's 128 outputs
    const int t  = threadIdx.x;         // 0..255

    const int m0   = mt * BM;
    const int lane = t & 63;
    const int wid  = t >> 6;
    const int wm   = wid >> 1;   // 0..1 (32 batch rows each)
    const int wn   = wid & 1;    // 0..1 (32 features each)
    const int r16  = lane & 15;
    const int kq   = lane >> 4;  // 0..3

    // ---- stage W half-fold -> Bs (fp32 -> bf16, swizzled): 64x128 ----
    const float* __restrict__ Wf = W + (size_t)f * (LOCAL * 128) + (size_t)bn0 * 128;
    #pragma unroll
    for (int it = 0; it < 4; ++it) {
        const int e   = it * 2048 + t * 8;
        const int row = e >> 7;        // l within half-fold (0..63)
        const int col = e & 127;       // k
        const float* g = Wf + row * 128 + col;
        f32x4 v0 = *(const f32x4*)g;
        f32x4 v1 = *(const f32x4*)(g + 4);
        cvt_store8((char*)Bs, (row * 256 + col * 2) ^ ((row & 7) << 4), v0, v1);
    }

    // ---- stage x tile -> As (fp32 -> bf16, swizzled): 64x128 ----
    const float* __restrict__ xg = x + (size_t)m0 * INF + (size_t)f * 64;
    #pragma unroll
    for (int it = 0; it < 4; ++it) {
        const int e   = it * 2048 + t * 8;
        const int row = e >> 7;        // batch row within tile (0..63)
        const int col = e & 127;       // k
        const float* g = xg + (size_t)row * INF + col;
        f32x4 v0 = *(const f32x4*)g;
        f32x4 v1 = *(const f32x4*)(g + 4);
        cvt_store8((char*)As, (row * 256 + col * 2) ^ ((row & 7) << 4), v0, v1);
    }
    __syncthreads();

    // ---- bias folded into accumulator init (bias depends on n only) ----
    float bv[2];
    #pragma unroll
    for (int j = 0; j < 2; ++j)
        bv[j] = bias[f * LOCAL + bn0 + wn * 32 + j * 16 + r16];

    f32x4 acc[2][2];
    #pragma unroll
    for (int i = 0; i < 2; ++i)
        #pragma unroll
        for (int j = 0; j < 2; ++j)
            acc[i][j] = (f32x4){bv[j], bv[j], bv[j], bv[j]};

    // ---- compute: 4 waves in 2x2, each 32x32 output; 4 MFMA per k-slice ----
    #pragma unroll
    for (int ks = 0; ks < 4; ++ks) {
        const int kof = ks * 32 + kq * 8;
        bf16x8 a[2], b[2];
        #pragma unroll
        for (int i = 0; i < 2; ++i) {
            const int row  = wm * 32 + i * 16 + r16;
            const int byte = (row * 256 + kof * 2) ^ ((row & 7) << 4);
            a[i] = *(const bf16x8*)((const char*)As + byte);
        }
        #pragma unroll
        for (int j = 0; j < 2; ++j) {
            const int row  = wn * 32 + j * 16 + r16;
            const int byte = (row * 256 + kof * 2) ^ ((row & 7) << 4);
            b[j] = *(const bf16x8*)((const char*)Bs + byte);
        }
        #pragma unroll
        for (int i = 0; i < 2; ++i)
            #pragma unroll
            for (int j = 0; j < 2; ++j)
                acc[i][j] = __builtin_amdgcn_mfma_f32_16x16x32_bf16(a[i], b[j], acc[i][j], 0, 0, 0);
    }

    // ---- epilogue: plain fp32 stores (bias already in acc) ----
    // C/D map: n = lane&15, m = (lane>>4)*4 + reg
    #pragma unroll
    for (int i = 0; i < 2; ++i) {
        const int mrow = m0 + wm * 32 + i * 16 + kq * 4;
        #pragma unroll
        for (int j = 0; j < 2; ++j) {
            const int ncol = f * LOCAL + bn0 + wn * 32 + j * 16 + r16;
            float* o = out + (size_t)mrow * OUTF + ncol;
            #pragma unroll
            for (int r = 0; r < 4; ++r)
                o[(size_t)r * OUTF] = acc[i][j][r];
        }
    }
}

extern "C" void kernel_launch(void* const* d_in, const int* in_sizes, int n_in,
                              void* d_out, int out_size, void* d_ws, size_t ws_size,
                              hipStream_t stream) {
    const float* x    = (const float*)d_in[0];
    const float* W    = (const float*)d_in[1];
    const float* bias = (const float*)d_in[2];
    float* out        = (float*)d_out;

    dim3 grid(FOLDS * 2, 2048 / BM);   // 254 x 32 blocks, fn fast
    dim3 block(256);
    local_linear_kernel<<<grid, block, 0, stream>>>(x, W, bias, out);
}

// Round 13
// 45.576 us; speedup vs baseline: 2.1318x; 2.1318x over previous
//
#include <hip/hip_runtime.h>
#include <hip/hip_bf16.h>

typedef float f32x4 __attribute__((ext_vector_type(4)));
typedef __bf16 bf16x8 __attribute__((ext_vector_type(8)));

#define INF   8192             // in_features
#define FOLDS 127
#define LOCAL 128
#define OUTF  (FOLDS * LOCAL)  // 16256
#define BM    64               // batch rows per tile
#define BN    64               // output features per block (half a fold)

// As/Bs: 64 rows x 128 cols bf16 (row stride 256B), XOR swizzle byte ^= (row&7)<<4
__device__ __forceinline__ void cvt_store8(char* lds, int byte, f32x4 v0, f32x4 v1) {
    bf16x8 w;
    w[0] = (__bf16)v0[0]; w[1] = (__bf16)v0[1]; w[2] = (__bf16)v0[2]; w[3] = (__bf16)v0[3];
    w[4] = (__bf16)v1[0]; w[5] = (__bf16)v1[1]; w[6] = (__bf16)v1[2]; w[7] = (__bf16)v1[3];
    *(bf16x8*)(lds + byte) = w;
}

__global__ __launch_bounds__(256, 5)   // 32 KB LDS -> 5 blocks/CU, 20 waves/CU
void local_linear_kernel(const float* __restrict__ x,
                         const float* __restrict__ W,
                         const float* __restrict__ bias,
                         float* __restrict__ out)
{
    __shared__ __align__(16) __bf16 As[BM * 128];   // x tile, 16 KiB (reused for tile 1)
    __shared__ __align__(16) __bf16 Bs[BN * 128];   // W half-fold, 16 KiB

    const int mt2 = blockIdx.x;         // 128-row group 0..15
    const int fn  = blockIdx.y;         // fold-half 0..253
    const int f   = fn >> 1;            // fold 0..126
    const int bn0 = (fn & 1) * BN;      // 0 or 64
    const int t   = threadIdx.x;        // 0..255

    const int m0   = mt2 * 2 * BM;      // tile0 rows m0.., tile1 rows m0+64..
    const int lane = t & 63;
    const int wid  = t >> 6;
    const int wm   = wid >> 1;   // 0..1 (32 batch rows each)
    const int wn   = wid & 1;    // 0..1 (32 features each)
    const int r16  = lane & 15;
    const int kq   = lane >> 4;  // 0..3

    // per-thread staging coordinates (shared by all stage loops)
    // it in 0..3: e = it*2048 + t*8, row = e>>7 (0..63), col = e&127

    // ---- stage W half-fold -> Bs ----
    const float* __restrict__ Wf = W + (size_t)f * (LOCAL * 128) + (size_t)bn0 * 128;
    #pragma unroll
    for (int it = 0; it < 4; ++it) {
        const int e = it * 2048 + t * 8;
        const int row = e >> 7, col = e & 127;
        const float* g = Wf + row * 128 + col;
        f32x4 v0 = *(const f32x4*)g;
        f32x4 v1 = *(const f32x4*)(g + 4);
        cvt_store8((char*)Bs, (row * 256 + col * 2) ^ ((row & 7) << 4), v0, v1);
    }

    // ---- stage x tile0 -> As ----
    const float* __restrict__ xg = x + (size_t)m0 * INF + (size_t)f * 64;
    #pragma unroll
    for (int it = 0; it < 4; ++it) {
        const int e = it * 2048 + t * 8;
        const int row = e >> 7, col = e & 127;
        const float* g = xg + (size_t)row * INF + col;
        f32x4 v0 = *(const f32x4*)g;
        f32x4 v1 = *(const f32x4*)(g + 4);
        cvt_store8((char*)As, (row * 256 + col * 2) ^ ((row & 7) << 4), v0, v1);
    }

    // bias (n dim) -> acc init
    float bv[2];
    #pragma unroll
    for (int j = 0; j < 2; ++j)
        bv[j] = bias[f * LOCAL + bn0 + wn * 32 + j * 16 + r16];

    __syncthreads();   // full drain once: Bs + As(tile0) visible

    // ---- prefetch tile1 into REGISTERS: in flight across tile0's compute ----
    f32x4 pre[8];
    {
        const float* __restrict__ xg1 = xg + (size_t)BM * INF;
        #pragma unroll
        for (int it = 0; it < 4; ++it) {
            const int e = it * 2048 + t * 8;
            const int row = e >> 7, col = e & 127;
            const float* g = xg1 + (size_t)row * INF + col;
            pre[it * 2 + 0] = *(const f32x4*)g;
            pre[it * 2 + 1] = *(const f32x4*)(g + 4);
        }
    }
    __builtin_amdgcn_sched_barrier(0);   // pin load issue here (don't sink to use)

    // ================= tile 0: compute + store =================
    {
        f32x4 acc[2][2];
        #pragma unroll
        for (int i = 0; i < 2; ++i)
            #pragma unroll
            for (int j = 0; j < 2; ++j)
                acc[i][j] = (f32x4){bv[j], bv[j], bv[j], bv[j]};

        #pragma unroll
        for (int ks = 0; ks < 4; ++ks) {
            const int kof = ks * 32 + kq * 8;
            bf16x8 a[2], b[2];
            #pragma unroll
            for (int i = 0; i < 2; ++i) {
                const int row  = wm * 32 + i * 16 + r16;
                const int byte = (row * 256 + kof * 2) ^ ((row & 7) << 4);
                a[i] = *(const bf16x8*)((const char*)As + byte);
            }
            #pragma unroll
            for (int j = 0; j < 2; ++j) {
                const int row  = wn * 32 + j * 16 + r16;
                const int byte = (row * 256 + kof * 2) ^ ((row & 7) << 4);
                b[j] = *(const bf16x8*)((const char*)Bs + byte);
            }
            #pragma unroll
            for (int i = 0; i < 2; ++i)
                #pragma unroll
                for (int j = 0; j < 2; ++j)
                    acc[i][j] = __builtin_amdgcn_mfma_f32_16x16x32_bf16(a[i], b[j], acc[i][j], 0, 0, 0);
        }

        #pragma unroll
        for (int i = 0; i < 2; ++i) {
            const int mrow = m0 + wm * 32 + i * 16 + kq * 4;   // C/D: m = kq*4 + reg
            #pragma unroll
            for (int j = 0; j < 2; ++j) {
                const int ncol = f * LOCAL + bn0 + wn * 32 + j * 16 + r16;  // n = lane&15
                float* o = out + (size_t)mrow * OUTF + ncol;
                #pragma unroll
                for (int r = 0; r < 4; ++r)
                    o[(size_t)r * OUTF] = acc[i][j][r];
            }
        }
    }

    // ================= swap As to tile1 (stores stay in flight) =================
    __builtin_amdgcn_sched_barrier(0);
    __builtin_amdgcn_s_barrier();                         // all waves done reading As
    asm volatile("s_waitcnt vmcnt(16)" ::: "memory");     // pre[] arrived; 16 stores flying
    __builtin_amdgcn_sched_barrier(0);
    #pragma unroll
    for (int it = 0; it < 4; ++it) {
        const int e = it * 2048 + t * 8;
        const int row = e >> 7, col = e & 127;
        cvt_store8((char*)As, (row * 256 + col * 2) ^ ((row & 7) << 4),
                   pre[it * 2 + 0], pre[it * 2 + 1]);
    }
    asm volatile("s_waitcnt lgkmcnt(0)" ::: "memory");
    __builtin_amdgcn_s_barrier();
    __builtin_amdgcn_sched_barrier(0);

    // ================= tile 1: compute + store =================
    {
        const int m1 = m0 + BM;
        f32x4 acc[2][2];
        #pragma unroll
        for (int i = 0; i < 2; ++i)
            #pragma unroll
            for (int j = 0; j < 2; ++j)
                acc[i][j] = (f32x4){bv[j], bv[j], bv[j], bv[j]};

        #pragma unroll
        for (int ks = 0; ks < 4; ++ks) {
            const int kof = ks * 32 + kq * 8;
            bf16x8 a[2], b[2];
            #pragma unroll
            for (int i = 0; i < 2; ++i) {
                const int row  = wm * 32 + i * 16 + r16;
                const int byte = (row * 256 + kof * 2) ^ ((row & 7) << 4);
                a[i] = *(const bf16x8*)((const char*)As + byte);
            }
            #pragma unroll
            for (int j = 0; j < 2; ++j) {
                const int row  = wn * 32 + j * 16 + r16;
                const int byte = (row * 256 + kof * 2) ^ ((row & 7) << 4);
                b[j] = *(const bf16x8*)((const char*)Bs + byte);
            }
            #pragma unroll
            for (int i = 0; i < 2; ++i)
                #pragma unroll
                for (int j = 0; j < 2; ++j)
                    acc[i][j] = __builtin_amdgcn_mfma_f32_16x16x32_bf16(a[i], b[j], acc[i][j], 0, 0, 0);
        }

        #pragma unroll
        for (int i = 0; i < 2; ++i) {
            const int mrow = m1 + wm * 32 + i * 16 + kq * 4;
            #pragma unroll
            for (int j = 0; j < 2; ++j) {
                const int ncol = f * LOCAL + bn0 + wn * 32 + j * 16 + r16;
                float* o = out + (size_t)mrow * OUTF + ncol;
                #pragma unroll
                for (int r = 0; r < 4; ++r)
                    o[(size_t)r * OUTF] = acc[i][j][r];
            }
        }
    }
}

extern "C" void kernel_launch(void* const* d_in, const int* in_sizes, int n_in,
                              void* d_out, int out_size, void* d_ws, size_t ws_size,
                              hipStream_t stream) {
    const float* x    = (const float*)d_in[0];
    const float* W    = (const float*)d_in[1];
    const float* bias = (const float*)d_in[2];
    float* out        = (float*)d_out;

    dim3 grid(2048 / (2 * BM), FOLDS * 2);   // 16 x 254 = 4064 blocks, mt fast
    dim3 block(256);
    local_linear_kernel<<<grid, block, 0, stream>>>(x, W, bias, out);
}